// Round 10
// baseline (441.598 us; speedup 1.0000x reference)
//
// Round 10: staggered exchange. All waves compute both layers sequentially:
// P1=l2(t-1) -> publish h2+F2; P2=l1(t) (hides F2 RT) -> publish h1+F1;
// poll F2 (1 probe), readback h2 (hides F1 RT), poll F1, readback h1.
// Narrow protocol (r8-proven): 1 flag store/WG/phase, wave0-only polls.
// W[2][16]=128 VGPR/wave, hf reg-reuse (24 frags/wave/step), parity-2 H bufs.
#include <hip/hip_runtime.h>

typedef unsigned short u16;
typedef unsigned int   u32;
typedef __attribute__((ext_vector_type(8))) short bf16x8;  // 8 bf16 (4 VGPRs)
typedef __attribute__((ext_vector_type(4))) float f32x4;   // MFMA C/D frag

#define DEVINL static __device__ __forceinline__
#define MFMA __builtin_amdgcn_mfma_f32_16x16x32_bf16

DEVINL u16 f2bf(float f){ u32 x = __float_as_uint(f); return (u16)((x + 0x7fffu + ((x>>16)&1u)) >> 16); }
DEVINL float bf2f(u16 u){ return __uint_as_float(((u32)u) << 16); }
DEVINL u32 pack2(float a, float b){ return (u32)f2bf(a) | ((u32)f2bf(b) << 16); }
DEVINL float sigm(float x){ return 1.f/(1.f + __expf(-x)); }
DEVINL float tanhs(float x){ float xc = fminf(fmaxf(x,-15.f),15.f); float e = __expf(2.f*xc); return (e-1.f)/(e+1.f); }
DEVINL void g_store(u32* p, u32 v){ __hip_atomic_store(p, v, __ATOMIC_RELAXED, __HIP_MEMORY_SCOPE_AGENT); }
DEVINL u32  g_load(const u32* p){ return __hip_atomic_load(p, __ATOMIC_RELAXED, __HIP_MEMORY_SCOPE_AGENT); }

// ---------------- prep: pack weights to bf16 with row permutation j' = u*4+gate
// matrix order m: 0 eIH_l0, 1 eHH_l0, 2 eIH_l1, 3 eHH_l1, 4 dIH_l0, 5 dHH_l0, 6 dIH_l1, 7 dHH_l1
__global__ void pack_all(const float* __restrict__ eih, const float* __restrict__ ehh,
                         const float* __restrict__ dih, const float* __restrict__ dhh,
                         const float* __restrict__ ebi, const float* __restrict__ ebh,
                         const float* __restrict__ dbi, const float* __restrict__ dbh,
                         u16* __restrict__ wout, float* __restrict__ bout,
                         u32* __restrict__ flags){
  int blk = blockIdx.x, t = threadIdx.x;
  if (blk < 8192){
    int m = blk >> 10, j2 = blk & 1023;
    const float* base = (m < 4) ? ((m & 1) ? ehh : eih) : ((m & 1) ? dhh : dih);
    const float* S = base + (size_t)((m >> 1) & 1) * 262144;  // layer select
    int u = j2 >> 2, g = j2 & 3, j = g*256 + u;
    wout[(size_t)blk*256 + t] = f2bf(S[(size_t)j*256 + t]);
  } else if (blk < 8208){
    int idx = (blk - 8192)*256 + t;             // 0..4095 : [phase][layer][j']
    int phase = idx >> 11, l = (idx >> 10) & 1, j2 = idx & 1023;
    int u = j2 >> 2, g = j2 & 3, j = g*256 + u;
    const float* bi = phase ? dbi : ebi;
    const float* bh = phase ? dbh : ebh;
    bout[idx] = bi[l*1024 + j] + bh[l*1024 + j];
  } else {
    for (int i = t; i < 2048; i += 256) flags[i] = 0u;   // flag reset EVERY call
  }
}

struct SM {
  u16   X[16][264];       // x(t)
  u16   H1t[16][264];     // h1(t-1) at step start
  u16   H2t[16][264];     // h2(t-2) at step start, h2(t-1) after readback
  float fcw[4][256];
  float fcb[4];
  int   tok[63][16];
};

__global__ void __launch_bounds__(512, 2)
lstm_main(const int* __restrict__ src, const float* __restrict__ enc_emb,
          const float* __restrict__ dec_emb, const u16* __restrict__ wpack,
          const float* __restrict__ bpack, const float* __restrict__ fcW,
          const float* __restrict__ fcb, float* __restrict__ out,
          u32* __restrict__ H1, u32* __restrict__ H2, u32* __restrict__ flags)
{
  __shared__ SM sm;
  const int tid  = threadIdx.x;
  const int wv   = tid >> 6;          // wave 0..7
  const int lane = tid & 63;
  const int agrp = lane >> 4;         // k-group
  const int n    = lane & 15;         // batch row
  const int gid  = blockIdx.x & 31;   // batch group (same XCD across slices)
  const int w    = blockIdx.x >> 5;   // column-slice 0..7
  const int wgb0 = gid << 4;
  const int xr   = tid >> 5, xk = (tid & 31) << 3;     // x-gather: row, u16-col
  const bool pub = (agrp & 1) == 0;
  const int jrow = (w << 7) + (wv << 4) + n;           // permuted gate row j'
  const int uu   = (w << 5) + (wv << 2) + agrp;        // unit owned by lane
  const int pw   = (w << 4) + (wv << 1) + (agrp >> 1); // u32 word in H slice

  // ---- prologue staging
  for (int i = tid; i < 1008; i += 512){
    int s = i >> 4, b = i & 15;
    int t = (s < 31) ? (31 - s) : (s - 31);   // enc reversed, then dec forward
    sm.tok[s][b] = src[t*512 + wgb0 + b];
  }
  for (int i = tid; i < 1024; i += 512) ((float*)sm.fcw)[i] = fcW[i];
  if (tid < 4) sm.fcb[tid] = fcb[tid];
  for (int i = tid; i < 2112; i += 512){      // zero h tiles
    ((u32*)sm.H1t)[i] = 0u;
    ((u32*)sm.H2t)[i] = 0u;
  }
  __syncthreads();
  { // x(0) -> X
    int tk = sm.tok[0][xr];
    const float* e = enc_emb + (size_t)tk*256 + xk;
    float4 v0 = *(const float4*)e, v1 = *(const float4*)(e + 4);
    u32* d = (u32*)&sm.X[xr][xk];
    d[0]=pack2(v0.x,v0.y); d[1]=pack2(v0.z,v0.w); d[2]=pack2(v1.x,v1.y); d[3]=pack2(v1.z,v1.w);
  }
  float4 xc0, xc1;                            // x(t+1) held in regs
  { // issue x(1)
    int tk = sm.tok[1][xr];
    const float* e = enc_emb + (size_t)tk*256 + xk;
    xc0 = *(const float4*)e; xc1 = *(const float4*)(e + 4);
  }

  // ---- weight-stationary: W[2][16] = 128 VGPR + bias
  bf16x8 W[2][16];
  float4 br[2];
  float  c1 = 0.f, c2s = 0.f;

  auto LOADW_L = [&](int ph, int l){
    const u16* base = wpack + (size_t)ph * 1048576;
    #pragma unroll
    for (int kk = 0; kk < 16; kk++){
      const u16* mp = base + (size_t)((l << 1) + (kk >> 3))*262144
                    + (size_t)jrow*256 + ((kk & 7) << 5) + (agrp << 3);
      W[l][kk] = *(const bf16x8*)mp;
    }
    br[l] = *(const float4*)(bpack + (((ph << 1) + l) << 10) + (uu << 2));
  };
  LOADW_L(0, 0); LOADW_L(0, 1);
  __syncthreads();

  auto step = [&](int t){
    const int parH1 = t & 1;              // parity of h1(t)
    const int parH2 = (t + 1) & 1;        // parity of h2(t-1)
    // ---- hf = h1(t-1) fragments, shared by P1 (l2 k-lo) and P2 (l1 k-hi)
    bf16x8 hf[8];
    #pragma unroll
    for (int kk = 0; kk < 8; kk++)
      hf[kk] = *(const bf16x8*)&sm.H1t[n][(kk << 5) + (agrp << 3)];
    // ---------- P1: l2(t-1) -> publish h2(t-1)
    if (t >= 1){
      f32x4 a2 = {0.f,0.f,0.f,0.f};
      #pragma unroll
      for (int kk = 0; kk < 8; kk++)
        a2 = MFMA(W[1][kk], hf[kk], a2, 0, 0, 0);
      #pragma unroll
      for (int kk = 0; kk < 8; kk++){
        bf16x8 b2 = *(const bf16x8*)&sm.H2t[n][(kk << 5) + (agrp << 3)];
        a2 = MFMA(W[1][8 + kk], b2, a2, 0, 0, 0);
      }
      float I = sigm(a2[0] + br[1].x), F = sigm(a2[1] + br[1].y);
      float G = tanhs(a2[2] + br[1].z), O = sigm(a2[3] + br[1].w);
      float cn = F*c2s + I*G; c2s = cn;
      u16 hb = f2bf(O * tanhs(cn));
      u32 other = (u32)__shfl_xor((int)(u32)hb, 16);
      if (pub)
        g_store(H2 + ((size_t)parH2*32 + gid)*2048 + n*128 + pw, (u32)hb | (other << 16));
    }
    asm volatile("s_waitcnt vmcnt(0)" ::: "memory");
    __syncthreads();                                   // B1: h2 publishes drained
    if (tid == 0) g_store(&flags[gid*16 + 8 + w], (u32)(t + 1));   // F2
    // ---------- P2: l1(t) -> publish h1(t)   (hides F2 visibility RT)
    if (t <= 62){
      f32x4 a1 = {0.f,0.f,0.f,0.f};
      #pragma unroll
      for (int kk = 0; kk < 8; kk++){
        bf16x8 bx = *(const bf16x8*)&sm.X[n][(kk << 5) + (agrp << 3)];
        a1 = MFMA(W[0][kk], bx, a1, 0, 0, 0);
      }
      #pragma unroll
      for (int kk = 0; kk < 8; kk++)
        a1 = MFMA(W[0][8 + kk], hf[kk], a1, 0, 0, 0);
      float I = sigm(a1[0] + br[0].x), F = sigm(a1[1] + br[0].y);
      float G = tanhs(a1[2] + br[0].z), O = sigm(a1[3] + br[0].w);
      float cn = F*c1 + I*G; c1 = cn;
      u16 hb = f2bf(O * tanhs(cn));
      u32 other = (u32)__shfl_xor((int)(u32)hb, 16);
      if (pub)
        g_store(H1 + ((size_t)parH1*32 + gid)*2048 + n*128 + pw, (u32)hb | (other << 16));
    }
    asm volatile("s_waitcnt vmcnt(0)" ::: "memory");
    __syncthreads();                                   // B2: h1 publishes drained
    if (tid == 0 && t <= 62) g_store(&flags[gid*16 + w], (u32)(t + 1));  // F1
    if (wv == 0){                                      // poll F2 (posted ~P2 ago)
      const u32 tgt = (u32)(t + 1);
      const bool mine = (lane >= 8) && (lane < 16);
      for (;;){
        u32 v = mine ? g_load(&flags[gid*16 + lane]) : tgt;
        if (__all(v >= tgt)) break;
        __builtin_amdgcn_s_sleep(1);
      }
    }
    __syncthreads();                                   // B3
    { // readback h2(t-1) -> H2t  (+ x(t+1) regs -> X)   (hides F1 RT)
      const int q = tid << 2, r = tid >> 5, p = q & 127;
      if (t >= 1){
        const u32* h2r = H2 + ((size_t)parH2*32 + gid)*2048;
        u32 w0 = g_load(h2r+q), w1 = g_load(h2r+q+1), w2 = g_load(h2r+q+2), w3 = g_load(h2r+q+3);
        u32* d2 = (u32*)&sm.H2t[r][p << 1];
        d2[0]=w0; d2[1]=w1; d2[2]=w2; d2[3]=w3;
      }
      if (t + 1 < 63){
        u32* d = (u32*)&sm.X[xr][xk];
        d[0]=pack2(xc0.x,xc0.y); d[1]=pack2(xc0.z,xc0.w);
        d[2]=pack2(xc1.x,xc1.y); d[3]=pack2(xc1.z,xc1.w);
      }
    }
    if (wv == 0 && t <= 62){                           // poll F1
      const u32 tgt = (u32)(t + 1);
      const bool mine = lane < 8;
      for (;;){
        u32 v = mine ? g_load(&flags[gid*16 + lane]) : tgt;
        if (__all(v >= tgt)) break;
        __builtin_amdgcn_s_sleep(1);
      }
    }
    __syncthreads();                                   // B4
    { // readback h1(t) -> H1t + issue x(t+2)
      const int q = tid << 2, r = tid >> 5, p = q & 127;
      if (t <= 62){
        const u32* h1r = H1 + ((size_t)parH1*32 + gid)*2048;
        u32 v0 = g_load(h1r+q), v1 = g_load(h1r+q+1), v2 = g_load(h1r+q+2), v3 = g_load(h1r+q+3);
        u32* d1 = (u32*)&sm.H1t[r][p << 1];
        d1[0]=v0; d1[1]=v1; d1[2]=v2; d1[3]=v3;
      }
      if (t + 2 < 63){
        int tk = sm.tok[t+2][xr];
        const float* e = ((t+2) < 31 ? enc_emb : dec_emb) + (size_t)tk*256 + xk;
        xc0 = *(const float4*)e; xc1 = *(const float4*)(e + 4);
      }
    }
    __syncthreads();                                   // B5
    // ---- fc + log_softmax on h2(t-1) (now in H2t); overlaps next step's P1
    if (t >= 32 && tid < 128){
      const int b = (w << 1) + (tid >> 6), v = (tid >> 4) & 3, q16 = tid & 15;
      const u16* hrow = &sm.H2t[b][q16 << 4];
      const float* wr = &sm.fcw[v][q16 << 4];
      bf16x8 h0 = *(const bf16x8*)hrow, h1v = *(const bf16x8*)(hrow + 8);
      float s = 0.f;
      #pragma unroll
      for (int e = 0; e < 8; e++){
        s += bf2f((u16)h0[e]) * wr[e];
        s += bf2f((u16)h1v[e]) * wr[8 + e];
      }
      s += __shfl_xor(s, 1); s += __shfl_xor(s, 2);
      s += __shfl_xor(s, 4); s += __shfl_xor(s, 8);
      s += sm.fcb[v];
      float m = fmaxf(s, __shfl_xor(s, 16)); m = fmaxf(m, __shfl_xor(m, 32));
      float e_ = __expf(s - m);
      float es = e_ + __shfl_xor(e_, 16); es += __shfl_xor(es, 32);
      if (q16 == 0)
        out[((size_t)(t - 32)*512 + wgb0 + b)*4 + v] = s - m - __logf(es);
    }
  };

  for (int t = 0; t <= 30; ++t) step(t);
  LOADW_L(1, 0);            // dec W1 (first used by P2 of step 31: l1(31))
  step(31);
  LOADW_L(1, 1);            // dec W2 (first used by P1 of step 32: l2(31))
  for (int t = 32; t <= 63; ++t) step(t);   // t=63: P1=l2(62), fc(62) -> row 31
}

extern "C" void kernel_launch(void* const* d_in, const int* in_sizes, int n_in,
                              void* d_out, int out_size, void* d_ws, size_t ws_size,
                              hipStream_t stream){
  const int*   src     = (const int*)  d_in[0];
  const float* enc_emb = (const float*)d_in[2];
  const float* enc_Wih = (const float*)d_in[3];
  const float* enc_Whh = (const float*)d_in[4];
  const float* enc_bih = (const float*)d_in[5];
  const float* enc_bhh = (const float*)d_in[6];
  const float* dec_emb = (const float*)d_in[7];
  const float* dec_Wih = (const float*)d_in[8];
  const float* dec_Whh = (const float*)d_in[9];
  const float* dec_bih = (const float*)d_in[10];
  const float* dec_bhh = (const float*)d_in[11];
  const float* fcW     = (const float*)d_in[12];
  const float* fcb     = (const float*)d_in[13];
  float* out = (float*)d_out;
  (void)in_sizes; (void)n_in; (void)out_size; (void)ws_size;

  // ws: wpack 4MB | bpack 16KB | H1 512KB (2-parity) | H2 512KB | flags 8KB
  u16*   wpack = (u16*)d_ws;
  float* bpack = (float*)((char*)d_ws + 4194304);
  u32*   H1    = (u32*)((char*)d_ws + 4194304 + 16384);
  u32*   H2    = (u32*)((char*)d_ws + 4194304 + 16384 + 524288);
  u32*   flags = (u32*)((char*)d_ws + 4194304 + 16384 + 1048576);

  pack_all<<<8209, 256, 0, stream>>>(enc_Wih, enc_Whh, dec_Wih, dec_Whh,
                                     enc_bih, enc_bhh, dec_bih, dec_bhh,
                                     wpack, bpack, flags);
  lstm_main<<<256, 512, 0, stream>>>(src, enc_emb, dec_emb, wpack, bpack,
                                     fcW, fcb, out, H1, H2, flags);
}

// Round 11
// 352.381 us; speedup vs baseline: 1.2532x; 1.2532x over previous
//
// Round 11: r8 (258us, best) + three in-structure latency cuts:
// (1) SA barrier + tid0 flag -> per-wave vmcnt(0) + lane0 atomicAdd on ONE
//     counter per WG (poll width unchanged: 8 counters, wave0 only).
// (2) x(t+2) 2-step reg lookahead: issued in readback, written after SC ->
//     embedding HBM latency never inside the pre-flag drain.
// (3) fc as full-wave job on wave 1 in the poll slack (reads h2(t-2)).
// 2 barriers/step. Everything else r8-identical.
#include <hip/hip_runtime.h>

typedef unsigned short u16;
typedef unsigned int   u32;
typedef __attribute__((ext_vector_type(8))) short bf16x8;  // 8 bf16 (4 VGPRs)
typedef __attribute__((ext_vector_type(4))) float f32x4;   // MFMA C/D frag

#define DEVINL static __device__ __forceinline__
#define MFMA __builtin_amdgcn_mfma_f32_16x16x32_bf16

DEVINL u16 f2bf(float f){ u32 x = __float_as_uint(f); return (u16)((x + 0x7fffu + ((x>>16)&1u)) >> 16); }
DEVINL float bf2f(u16 u){ return __uint_as_float(((u32)u) << 16); }
DEVINL u32 pack2(float a, float b){ return (u32)f2bf(a) | ((u32)f2bf(b) << 16); }
DEVINL float sigm(float x){ return 1.f/(1.f + __expf(-x)); }
DEVINL float tanhs(float x){ float xc = fminf(fmaxf(x,-15.f),15.f); float e = __expf(2.f*xc); return (e-1.f)/(e+1.f); }
DEVINL void g_store(u32* p, u32 v){ __hip_atomic_store(p, v, __ATOMIC_RELAXED, __HIP_MEMORY_SCOPE_AGENT); }
DEVINL u32  g_load(const u32* p){ return __hip_atomic_load(p, __ATOMIC_RELAXED, __HIP_MEMORY_SCOPE_AGENT); }

// ---------------- prep: pack weights to bf16 with row permutation j' = u*4+gate
// matrix order m: 0 eIH_l0, 1 eHH_l0, 2 eIH_l1, 3 eHH_l1, 4 dIH_l0, 5 dHH_l0, 6 dIH_l1, 7 dHH_l1
__global__ void pack_all(const float* __restrict__ eih, const float* __restrict__ ehh,
                         const float* __restrict__ dih, const float* __restrict__ dhh,
                         const float* __restrict__ ebi, const float* __restrict__ ebh,
                         const float* __restrict__ dbi, const float* __restrict__ dbh,
                         u16* __restrict__ wout, float* __restrict__ bout,
                         u32* __restrict__ flags){
  int blk = blockIdx.x, t = threadIdx.x;
  if (blk < 8192){
    int m = blk >> 10, j2 = blk & 1023;
    const float* base = (m < 4) ? ((m & 1) ? ehh : eih) : ((m & 1) ? dhh : dih);
    const float* S = base + (size_t)((m >> 1) & 1) * 262144;  // layer select
    int u = j2 >> 2, g = j2 & 3, j = g*256 + u;
    wout[(size_t)blk*256 + t] = f2bf(S[(size_t)j*256 + t]);
  } else if (blk < 8208){
    int idx = (blk - 8192)*256 + t;             // 0..4095 : [phase][layer][j']
    int phase = idx >> 11, l = (idx >> 10) & 1, j2 = idx & 1023;
    int u = j2 >> 2, g = j2 & 3, j = g*256 + u;
    const float* bi = phase ? dbi : ebi;
    const float* bh = phase ? dbh : ebh;
    bout[idx] = bi[l*1024 + j] + bh[l*1024 + j];
  } else {
    for (int i = t; i < 2048; i += 256) flags[i] = 0u;   // counter reset EVERY call
  }
}

struct SM {
  u16   X[16][264];       // x(t)
  u16   H1t[16][264];     // h1(t-1) at compute time
  u16   H2t[16][264];     // h2(t-2) at compute time; h2(t-1) after readback
  float fcw[4][256];
  float fcb[4];
  int   tok[63][16];
};

__global__ void __launch_bounds__(512, 2)
lstm_main(const int* __restrict__ src, const float* __restrict__ enc_emb,
          const float* __restrict__ dec_emb, const u16* __restrict__ wpack,
          const float* __restrict__ bpack, const float* __restrict__ fcW,
          const float* __restrict__ fcb, float* __restrict__ out,
          u32* __restrict__ H1, u32* __restrict__ H2, u32* __restrict__ flags)
{
  __shared__ SM sm;
  const int tid  = threadIdx.x;
  const int wv   = tid >> 6;          // wave 0..7
  const int lane = tid & 63;
  const int agrp = lane >> 4;         // k-group
  const int n    = lane & 15;         // batch row
  const int gid  = blockIdx.x & 31;   // batch group (same XCD across slices)
  const int w    = blockIdx.x >> 5;   // column-slice 0..7
  const int wgb0 = gid << 4;
  const int xr   = tid >> 5, xk = (tid & 31) << 3;     // x-gather: row, u16-col
  const int myl  = wv >> 2;           // 0: layer1-wave, 1: layer2-wave
  const int wq   = wv & 3;            // quarter within role
  const bool pub = (agrp & 1) == 0;
  const int jrow0 = (w << 7) + (wq << 5) + n;          // gate row j', tile ct=0
  const int jrow1 = jrow0 + 16;                        // tile ct=1
  const int uu0   = (w << 5) + (wq << 3) + agrp;       // unit, tile ct=0
  const int uu1   = uu0 + 4;
  const int pw0   = (w << 4) + (wq << 2) + (agrp >> 1);// u32 word, tile ct=0
  const int pw1   = pw0 + 2;

  // ---- prologue staging
  for (int i = tid; i < 1008; i += 512){
    int s = i >> 4, b = i & 15;
    int t = (s < 31) ? (31 - s) : (s - 31);   // enc reversed, then dec forward
    sm.tok[s][b] = src[t*512 + wgb0 + b];
  }
  for (int i = tid; i < 1024; i += 512) ((float*)sm.fcw)[i] = fcW[i];
  if (tid < 4) sm.fcb[tid] = fcb[tid];
  for (int i = tid; i < 2112; i += 512){      // zero h tiles
    ((u32*)sm.H1t)[i] = 0u;
    ((u32*)sm.H2t)[i] = 0u;
  }
  __syncthreads();
  { // x(0) -> X
    int tk = sm.tok[0][xr];
    const float* e = enc_emb + (size_t)tk*256 + xk;
    float4 v0 = *(const float4*)e, v1 = *(const float4*)(e + 4);
    u32* d = (u32*)&sm.X[xr][xk];
    d[0]=pack2(v0.x,v0.y); d[1]=pack2(v0.z,v0.w); d[2]=pack2(v1.x,v1.y); d[3]=pack2(v1.z,v1.w);
  }
  float4 xh0, xh1;                            // x(t+1) held in regs
  { // issue x(1)
    int tk = sm.tok[1][xr];
    const float* e = enc_emb + (size_t)tk*256 + xk;
    xh0 = *(const float4*)e; xh1 = *(const float4*)(e + 4);
  }

  // ---- weight-stationary: my layer's 2 gate-tiles, W[2][16] = 128 regs
  bf16x8 W[2][16];
  float4 br[2];
  float  cst[2] = {0.f, 0.f};

  auto LOADW = [&](int ph){
    const u16* base = wpack + (size_t)ph*1048576 + (size_t)myl*524288;
    #pragma unroll
    for (int kk = 0; kk < 16; kk++){
      const size_t moff = (size_t)(kk >> 3)*262144 + ((kk & 7) << 5) + (agrp << 3);
      W[0][kk] = *(const bf16x8*)(base + moff + (size_t)jrow0*256);
      W[1][kk] = *(const bf16x8*)(base + moff + (size_t)jrow1*256);
    }
    br[0] = *(const float4*)(bpack + (((ph << 1) + myl) << 10) + (uu0 << 2));
    br[1] = *(const float4*)(bpack + (((ph << 1) + myl) << 10) + (uu1 << 2));
  };
  LOADW(0);
  __syncthreads();

  auto step = [&](int t){
    // ---- compute my layer: l1(t) waves 0-3; l2(t-1) waves 4-7
    const bool active = myl ? (t >= 1) : (t <= 62);
    if (active){
      const u16 (*loT)[264] = myl ? sm.H1t : sm.X;    // l1: x(t)   ; l2: h1(t-1)
      const u16 (*hiT)[264] = myl ? sm.H2t : sm.H1t;  // l1: h1(t-1); l2: h2(t-2)
      f32x4 a0 = {0.f,0.f,0.f,0.f}, a1 = {0.f,0.f,0.f,0.f};
      #pragma unroll
      for (int kk = 0; kk < 8; kk++){
        bf16x8 b = *(const bf16x8*)&loT[n][(kk << 5) + (agrp << 3)];
        a0 = MFMA(W[0][kk], b, a0, 0, 0, 0);
        a1 = MFMA(W[1][kk], b, a1, 0, 0, 0);
      }
      #pragma unroll
      for (int kk = 0; kk < 8; kk++){
        bf16x8 b = *(const bf16x8*)&hiT[n][(kk << 5) + (agrp << 3)];
        a0 = MFMA(W[0][8 + kk], b, a0, 0, 0, 0);
        a1 = MFMA(W[1][8 + kk], b, a1, 0, 0, 0);
      }
      float I0 = sigm(a0[0] + br[0].x), F0 = sigm(a0[1] + br[0].y);
      float G0 = tanhs(a0[2] + br[0].z), O0 = sigm(a0[3] + br[0].w);
      float cn0 = F0*cst[0] + I0*G0; cst[0] = cn0;
      u16 h0 = f2bf(O0 * tanhs(cn0));
      float I1 = sigm(a1[0] + br[1].x), F1 = sigm(a1[1] + br[1].y);
      float G1 = tanhs(a1[2] + br[1].z), O1 = sigm(a1[3] + br[1].w);
      float cn1 = F1*cst[1] + I1*G1; cst[1] = cn1;
      u16 h1b = f2bf(O1 * tanhs(cn1));
      u32 o0 = (u32)__shfl_xor((int)(u32)h0, 16);
      u32 o1 = (u32)__shfl_xor((int)(u32)h1b, 16);
      const int ppar = myl ? ((t + 1) & 1) : (t & 1);   // l2 publishes h2(t-1)
      u32* Hp = (myl ? H2 : H1) + ((size_t)ppar*32 + gid)*2048 + n*128;
      if (pub){
        g_store(Hp + pw0, (u32)h0 | (o0 << 16));
        g_store(Hp + pw1, (u32)h1b | (o1 << 16));
      }
    }
    // ---- per-wave drain + shared-counter ack (replaces SA barrier + tid0 flag)
    asm volatile("s_waitcnt vmcnt(0)" ::: "memory");
    if (lane == 0)
      __hip_atomic_fetch_add(&flags[gid*8 + w], 1u, __ATOMIC_RELAXED, __HIP_MEMORY_SCOPE_AGENT);
    // ---- poll slack: wave0 polls, wave1 does fc for h2(t-2) -> out row t-33
    if (wv == 0){
      const u32 tgt = (u32)(8*(t + 1));
      for (;;){
        u32 v = (lane < 8) ? g_load(&flags[gid*8 + lane]) : tgt;
        if (__all(v >= tgt)) break;
        __builtin_amdgcn_s_sleep(1);
      }
    } else if (wv == 1 && t >= 33){
      const int b = (w << 1) + (lane >> 5), v = (lane >> 3) & 3, q8 = lane & 7;
      const u16* hrow = &sm.H2t[b][q8 << 5];
      const float* wr = &sm.fcw[v][q8 << 5];
      float s = 0.f;
      #pragma unroll
      for (int f = 0; f < 4; f++){
        bf16x8 hv = *(const bf16x8*)(hrow + (f << 3));
        const float4 wa = *(const float4*)(wr + (f << 3));
        const float4 wb = *(const float4*)(wr + (f << 3) + 4);
        s += bf2f((u16)hv[0])*wa.x + bf2f((u16)hv[1])*wa.y
           + bf2f((u16)hv[2])*wa.z + bf2f((u16)hv[3])*wa.w
           + bf2f((u16)hv[4])*wb.x + bf2f((u16)hv[5])*wb.y
           + bf2f((u16)hv[6])*wb.z + bf2f((u16)hv[7])*wb.w;
      }
      s += __shfl_xor(s, 1); s += __shfl_xor(s, 2); s += __shfl_xor(s, 4);
      s += sm.fcb[v];
      float m = fmaxf(s, __shfl_xor(s, 8)); m = fmaxf(m, __shfl_xor(m, 16));
      float e_ = __expf(s - m);
      float es = e_ + __shfl_xor(e_, 8); es += __shfl_xor(es, 16);
      if (q8 == 0)
        out[((size_t)(t - 33)*512 + wgb0 + b)*4 + v] = s - m - __logf(es);
    }
    __syncthreads();                                           // SC
    { // readback h1(t)/h2(t-1) -> LDS; x(t+1) regs -> X; issue x(t+2)
      const int q = tid << 2, r = tid >> 5, p = q & 127;
      if (t < 63){
        const u32* h1r = H1 + ((size_t)(t & 1)*32 + gid)*2048;
        u32 v0 = g_load(h1r+q), v1 = g_load(h1r+q+1), v2 = g_load(h1r+q+2), v3 = g_load(h1r+q+3);
        u32* d1 = (u32*)&sm.H1t[r][p << 1];
        d1[0]=v0; d1[1]=v1; d1[2]=v2; d1[3]=v3;
      }
      if (t > 0){
        const u32* h2r = H2 + ((size_t)((t - 1) & 1)*32 + gid)*2048;
        u32 w0 = g_load(h2r+q), w1 = g_load(h2r+q+1), w2 = g_load(h2r+q+2), w3 = g_load(h2r+q+3);
        u32* d2 = (u32*)&sm.H2t[r][p << 1];
        d2[0]=w0; d2[1]=w1; d2[2]=w2; d2[3]=w3;
      }
      if (t + 1 < 63){                   // x(t+1) regs (loaded last step) -> X
        u32* d = (u32*)&sm.X[xr][xk];
        d[0]=pack2(xh0.x,xh0.y); d[1]=pack2(xh0.z,xh0.w);
        d[2]=pack2(xh1.x,xh1.y); d[3]=pack2(xh1.z,xh1.w);
      }
      if (t + 2 < 63){                   // issue x(t+2) into held regs
        int tk = sm.tok[t+2][xr];
        const float* e = ((t+2) < 31 ? enc_emb : dec_emb) + (size_t)tk*256 + xk;
        xh0 = *(const float4*)e; xh1 = *(const float4*)(e + 4);
      }
    }
    __syncthreads();                                           // SD
  };

  for (int t = 0; t <= 30; ++t) step(t);
  if (myl == 0) LOADW(1);   // dec W1 (first used by l1(31)); l2(30) still enc W2
  step(31);
  if (myl == 1) LOADW(1);   // dec W2 (first used computing l2(31) at step 32)
  for (int t = 32; t <= 63; ++t) step(t);

  // ---- tail fc: h2(62) (in H2t after step 63's readback) -> out row 31
  if (wv == 1){
    const int b = (w << 1) + (lane >> 5), v = (lane >> 3) & 3, q8 = lane & 7;
    const u16* hrow = &sm.H2t[b][q8 << 5];
    const float* wr = &sm.fcw[v][q8 << 5];
    float s = 0.f;
    #pragma unroll
    for (int f = 0; f < 4; f++){
      bf16x8 hv = *(const bf16x8*)(hrow + (f << 3));
      const float4 wa = *(const float4*)(wr + (f << 3));
      const float4 wb = *(const float4*)(wr + (f << 3) + 4);
      s += bf2f((u16)hv[0])*wa.x + bf2f((u16)hv[1])*wa.y
         + bf2f((u16)hv[2])*wa.z + bf2f((u16)hv[3])*wa.w
         + bf2f((u16)hv[4])*wb.x + bf2f((u16)hv[5])*wb.y
         + bf2f((u16)hv[6])*wb.z + bf2f((u16)hv[7])*wb.w;
    }
    s += __shfl_xor(s, 1); s += __shfl_xor(s, 2); s += __shfl_xor(s, 4);
    s += sm.fcb[v];
    float m = fmaxf(s, __shfl_xor(s, 8)); m = fmaxf(m, __shfl_xor(m, 16));
    float e_ = __expf(s - m);
    float es = e_ + __shfl_xor(e_, 8); es += __shfl_xor(es, 16);
    if (q8 == 0)
      out[((size_t)31*512 + wgb0 + b)*4 + v] = s - m - __logf(es);
  }
}

extern "C" void kernel_launch(void* const* d_in, const int* in_sizes, int n_in,
                              void* d_out, int out_size, void* d_ws, size_t ws_size,
                              hipStream_t stream){
  const int*   src     = (const int*)  d_in[0];
  const float* enc_emb = (const float*)d_in[2];
  const float* enc_Wih = (const float*)d_in[3];
  const float* enc_Whh = (const float*)d_in[4];
  const float* enc_bih = (const float*)d_in[5];
  const float* enc_bhh = (const float*)d_in[6];
  const float* dec_emb = (const float*)d_in[7];
  const float* dec_Wih = (const float*)d_in[8];
  const float* dec_Whh = (const float*)d_in[9];
  const float* dec_bih = (const float*)d_in[10];
  const float* dec_bhh = (const float*)d_in[11];
  const float* fcW     = (const float*)d_in[12];
  const float* fcb     = (const float*)d_in[13];
  float* out = (float*)d_out;
  (void)in_sizes; (void)n_in; (void)out_size; (void)ws_size;

  // ws: wpack 4MB | bpack 16KB | H1 512KB (2-parity) | H2 512KB | flags 8KB
  u16*   wpack = (u16*)d_ws;
  float* bpack = (float*)((char*)d_ws + 4194304);
  u32*   H1    = (u32*)((char*)d_ws + 4194304 + 16384);
  u32*   H2    = (u32*)((char*)d_ws + 4194304 + 16384 + 524288);
  u32*   flags = (u32*)((char*)d_ws + 4194304 + 16384 + 1048576);

  pack_all<<<8209, 256, 0, stream>>>(enc_Wih, enc_Whh, dec_Wih, dec_Whh,
                                     enc_bih, enc_bhh, dec_bih, dec_bhh,
                                     wpack, bpack, flags);
  lstm_main<<<256, 512, 0, stream>>>(src, enc_emb, dec_emb, wpack, bpack,
                                     fcW, fcb, out, H1, H2, flags);
}

// Round 12
// 246.592 us; speedup vs baseline: 1.7908x; 1.4290x over previous
//
// Round 12: r8 protocol restored EXACTLY (SA barrier + tid0 single flag store +
// wave0-only poll = the proven narrow protocol), plus only r11's two clean wins:
// (a) x(t+2) 2-step reg lookahead (no HBM gather inside the SA drain),
// (b) full-wave fc on wave 1 in the poll slack (off the post-SD critical path).
// Wave-specialized layers (r8): waves 0-3 l1, 4-7 l2, W[2][16]=128 VGPR.
#include <hip/hip_runtime.h>

typedef unsigned short u16;
typedef unsigned int   u32;
typedef __attribute__((ext_vector_type(8))) short bf16x8;  // 8 bf16 (4 VGPRs)
typedef __attribute__((ext_vector_type(4))) float f32x4;   // MFMA C/D frag

#define DEVINL static __device__ __forceinline__
#define MFMA __builtin_amdgcn_mfma_f32_16x16x32_bf16

DEVINL u16 f2bf(float f){ u32 x = __float_as_uint(f); return (u16)((x + 0x7fffu + ((x>>16)&1u)) >> 16); }
DEVINL float bf2f(u16 u){ return __uint_as_float(((u32)u) << 16); }
DEVINL u32 pack2(float a, float b){ return (u32)f2bf(a) | ((u32)f2bf(b) << 16); }
DEVINL float sigm(float x){ return 1.f/(1.f + __expf(-x)); }
DEVINL float tanhs(float x){ float xc = fminf(fmaxf(x,-15.f),15.f); float e = __expf(2.f*xc); return (e-1.f)/(e+1.f); }
DEVINL void g_store(u32* p, u32 v){ __hip_atomic_store(p, v, __ATOMIC_RELAXED, __HIP_MEMORY_SCOPE_AGENT); }
DEVINL u32  g_load(const u32* p){ return __hip_atomic_load(p, __ATOMIC_RELAXED, __HIP_MEMORY_SCOPE_AGENT); }

// ---------------- prep: pack weights to bf16 with row permutation j' = u*4+gate
// matrix order m: 0 eIH_l0, 1 eHH_l0, 2 eIH_l1, 3 eHH_l1, 4 dIH_l0, 5 dHH_l0, 6 dIH_l1, 7 dHH_l1
__global__ void pack_all(const float* __restrict__ eih, const float* __restrict__ ehh,
                         const float* __restrict__ dih, const float* __restrict__ dhh,
                         const float* __restrict__ ebi, const float* __restrict__ ebh,
                         const float* __restrict__ dbi, const float* __restrict__ dbh,
                         u16* __restrict__ wout, float* __restrict__ bout,
                         u32* __restrict__ flags){
  int blk = blockIdx.x, t = threadIdx.x;
  if (blk < 8192){
    int m = blk >> 10, j2 = blk & 1023;
    const float* base = (m < 4) ? ((m & 1) ? ehh : eih) : ((m & 1) ? dhh : dih);
    const float* S = base + (size_t)((m >> 1) & 1) * 262144;  // layer select
    int u = j2 >> 2, g = j2 & 3, j = g*256 + u;
    wout[(size_t)blk*256 + t] = f2bf(S[(size_t)j*256 + t]);
  } else if (blk < 8208){
    int idx = (blk - 8192)*256 + t;             // 0..4095 : [phase][layer][j']
    int phase = idx >> 11, l = (idx >> 10) & 1, j2 = idx & 1023;
    int u = j2 >> 2, g = j2 & 3, j = g*256 + u;
    const float* bi = phase ? dbi : ebi;
    const float* bh = phase ? dbh : ebh;
    bout[idx] = bi[l*1024 + j] + bh[l*1024 + j];
  } else {
    for (int i = t; i < 2048; i += 256) flags[i] = 0u;   // flag reset EVERY call
  }
}

struct SM {
  u16   X[16][264];       // x(t)
  u16   H1t[16][264];     // h1(t-1) at compute time
  u16   H2t[16][264];     // h2(t-2) at compute time; h2(t-1) after readback
  float fcw[4][256];
  float fcb[4];
  int   tok[63][16];
};

__global__ void __launch_bounds__(512, 2)
lstm_main(const int* __restrict__ src, const float* __restrict__ enc_emb,
          const float* __restrict__ dec_emb, const u16* __restrict__ wpack,
          const float* __restrict__ bpack, const float* __restrict__ fcW,
          const float* __restrict__ fcb, float* __restrict__ out,
          u32* __restrict__ H1, u32* __restrict__ H2, u32* __restrict__ flags)
{
  __shared__ SM sm;
  const int tid  = threadIdx.x;
  const int wv   = tid >> 6;          // wave 0..7
  const int lane = tid & 63;
  const int agrp = lane >> 4;         // k-group
  const int n    = lane & 15;         // batch row
  const int gid  = blockIdx.x & 31;   // batch group (same XCD across slices)
  const int w    = blockIdx.x >> 5;   // column-slice 0..7
  const int wgb0 = gid << 4;
  const int xr   = tid >> 5, xk = (tid & 31) << 3;     // x-gather: row, u16-col
  const int myl  = wv >> 2;           // 0: layer1-wave, 1: layer2-wave
  const int wq   = wv & 3;            // quarter within role
  const bool pub = (agrp & 1) == 0;
  const int jrow0 = (w << 7) + (wq << 5) + n;          // gate row j', tile ct=0
  const int jrow1 = jrow0 + 16;                        // tile ct=1
  const int uu0   = (w << 5) + (wq << 3) + agrp;       // unit, tile ct=0
  const int uu1   = uu0 + 4;
  const int pw0   = (w << 4) + (wq << 2) + (agrp >> 1);// u32 word, tile ct=0
  const int pw1   = pw0 + 2;

  // ---- prologue staging
  for (int i = tid; i < 1008; i += 512){
    int s = i >> 4, b = i & 15;
    int t = (s < 31) ? (31 - s) : (s - 31);   // enc reversed, then dec forward
    sm.tok[s][b] = src[t*512 + wgb0 + b];
  }
  for (int i = tid; i < 1024; i += 512) ((float*)sm.fcw)[i] = fcW[i];
  if (tid < 4) sm.fcb[tid] = fcb[tid];
  for (int i = tid; i < 2112; i += 512){      // zero h tiles
    ((u32*)sm.H1t)[i] = 0u;
    ((u32*)sm.H2t)[i] = 0u;
  }
  __syncthreads();
  { // x(0) -> X
    int tk = sm.tok[0][xr];
    const float* e = enc_emb + (size_t)tk*256 + xk;
    float4 v0 = *(const float4*)e, v1 = *(const float4*)(e + 4);
    u32* d = (u32*)&sm.X[xr][xk];
    d[0]=pack2(v0.x,v0.y); d[1]=pack2(v0.z,v0.w); d[2]=pack2(v1.x,v1.y); d[3]=pack2(v1.z,v1.w);
  }
  float4 xh0, xh1;                            // x(t+1) held in regs
  { // issue x(1)
    int tk = sm.tok[1][xr];
    const float* e = enc_emb + (size_t)tk*256 + xk;
    xh0 = *(const float4*)e; xh1 = *(const float4*)(e + 4);
  }

  // ---- weight-stationary: my layer's 2 gate-tiles, W[2][16] = 128 regs
  bf16x8 W[2][16];
  float4 br[2];
  float  cst[2] = {0.f, 0.f};

  auto LOADW = [&](int ph){
    const u16* base = wpack + (size_t)ph*1048576 + (size_t)myl*524288;
    #pragma unroll
    for (int kk = 0; kk < 16; kk++){
      const size_t moff = (size_t)(kk >> 3)*262144 + ((kk & 7) << 5) + (agrp << 3);
      W[0][kk] = *(const bf16x8*)(base + moff + (size_t)jrow0*256);
      W[1][kk] = *(const bf16x8*)(base + moff + (size_t)jrow1*256);
    }
    br[0] = *(const float4*)(bpack + (((ph << 1) + myl) << 10) + (uu0 << 2));
    br[1] = *(const float4*)(bpack + (((ph << 1) + myl) << 10) + (uu1 << 2));
  };
  LOADW(0);
  __syncthreads();

  auto step = [&](int t){
    // ---- compute my layer: l1(t) waves 0-3; l2(t-1) waves 4-7
    const bool active = myl ? (t >= 1) : (t <= 62);
    if (active){
      const u16 (*loT)[264] = myl ? sm.H1t : sm.X;    // l1: x(t)   ; l2: h1(t-1)
      const u16 (*hiT)[264] = myl ? sm.H2t : sm.H1t;  // l1: h1(t-1); l2: h2(t-2)
      f32x4 a0 = {0.f,0.f,0.f,0.f}, a1 = {0.f,0.f,0.f,0.f};
      #pragma unroll
      for (int kk = 0; kk < 8; kk++){
        bf16x8 b = *(const bf16x8*)&loT[n][(kk << 5) + (agrp << 3)];
        a0 = MFMA(W[0][kk], b, a0, 0, 0, 0);
        a1 = MFMA(W[1][kk], b, a1, 0, 0, 0);
      }
      #pragma unroll
      for (int kk = 0; kk < 8; kk++){
        bf16x8 b = *(const bf16x8*)&hiT[n][(kk << 5) + (agrp << 3)];
        a0 = MFMA(W[0][8 + kk], b, a0, 0, 0, 0);
        a1 = MFMA(W[1][8 + kk], b, a1, 0, 0, 0);
      }
      float I0 = sigm(a0[0] + br[0].x), F0 = sigm(a0[1] + br[0].y);
      float G0 = tanhs(a0[2] + br[0].z), O0 = sigm(a0[3] + br[0].w);
      float cn0 = F0*cst[0] + I0*G0; cst[0] = cn0;
      u16 h0 = f2bf(O0 * tanhs(cn0));
      float I1 = sigm(a1[0] + br[1].x), F1 = sigm(a1[1] + br[1].y);
      float G1 = tanhs(a1[2] + br[1].z), O1 = sigm(a1[3] + br[1].w);
      float cn1 = F1*cst[1] + I1*G1; cst[1] = cn1;
      u16 h1b = f2bf(O1 * tanhs(cn1));
      u32 o0 = (u32)__shfl_xor((int)(u32)h0, 16);
      u32 o1 = (u32)__shfl_xor((int)(u32)h1b, 16);
      const int ppar = myl ? ((t + 1) & 1) : (t & 1);   // l2 publishes h2(t-1)
      u32* Hp = (myl ? H2 : H1) + ((size_t)ppar*32 + gid)*2048 + n*128;
      if (pub){
        g_store(Hp + pw0, (u32)h0 | (o0 << 16));
        g_store(Hp + pw1, (u32)h1b | (o1 << 16));
      }
    }
    __syncthreads();                                           // SA: stores drained
    if (tid == 0) g_store(&flags[gid*8 + w], (u32)(t + 1));
    // ---- poll slack: wave0 polls; wave1 does fc for h2(t-2) -> out row t-33
    if (wv == 0){
      const u32 tgt = (u32)(t + 1);
      const bool mine = lane < 8;
      for (;;){
        u32 v = mine ? g_load(&flags[gid*8 + lane]) : tgt;
        if (__all(v >= tgt)) break;
        __builtin_amdgcn_s_sleep(1);
      }
    } else if (wv == 1 && t >= 33){
      const int b = (w << 1) + (lane >> 5), v = (lane >> 3) & 3, q8 = lane & 7;
      const u16* hrow = &sm.H2t[b][q8 << 5];
      const float* wr = &sm.fcw[v][q8 << 5];
      float s = 0.f;
      #pragma unroll
      for (int f = 0; f < 4; f++){
        bf16x8 hv = *(const bf16x8*)(hrow + (f << 3));
        const float4 wa = *(const float4*)(wr + (f << 3));
        const float4 wb = *(const float4*)(wr + (f << 3) + 4);
        s += bf2f((u16)hv[0])*wa.x + bf2f((u16)hv[1])*wa.y
           + bf2f((u16)hv[2])*wa.z + bf2f((u16)hv[3])*wa.w
           + bf2f((u16)hv[4])*wb.x + bf2f((u16)hv[5])*wb.y
           + bf2f((u16)hv[6])*wb.z + bf2f((u16)hv[7])*wb.w;
      }
      s += __shfl_xor(s, 1); s += __shfl_xor(s, 2); s += __shfl_xor(s, 4);
      s += sm.fcb[v];
      float m = fmaxf(s, __shfl_xor(s, 8)); m = fmaxf(m, __shfl_xor(m, 16));
      float e_ = __expf(s - m);
      float es = e_ + __shfl_xor(e_, 8); es += __shfl_xor(es, 16);
      if (q8 == 0)
        out[((size_t)(t - 33)*512 + wgb0 + b)*4 + v] = s - m - __logf(es);
    }
    __syncthreads();                                           // SC
    { // readback h1(t)/h2(t-1) -> LDS; x(t+1) regs -> X; issue x(t+2)
      const int q = tid << 2, r = tid >> 5, p = q & 127;
      if (t < 63){
        const u32* h1r = H1 + ((size_t)(t & 1)*32 + gid)*2048;
        u32 v0 = g_load(h1r+q), v1 = g_load(h1r+q+1), v2 = g_load(h1r+q+2), v3 = g_load(h1r+q+3);
        u32* d1 = (u32*)&sm.H1t[r][p << 1];
        d1[0]=v0; d1[1]=v1; d1[2]=v2; d1[3]=v3;
      }
      if (t > 0){
        const u32* h2r = H2 + ((size_t)((t - 1) & 1)*32 + gid)*2048;
        u32 w0 = g_load(h2r+q), w1 = g_load(h2r+q+1), w2 = g_load(h2r+q+2), w3 = g_load(h2r+q+3);
        u32* d2 = (u32*)&sm.H2t[r][p << 1];
        d2[0]=w0; d2[1]=w1; d2[2]=w2; d2[3]=w3;
      }
      if (t + 1 < 63){                   // x(t+1) regs (loaded last step) -> X
        u32* d = (u32*)&sm.X[xr][xk];
        d[0]=pack2(xh0.x,xh0.y); d[1]=pack2(xh0.z,xh0.w);
        d[2]=pack2(xh1.x,xh1.y); d[3]=pack2(xh1.z,xh1.w);
      }
      if (t + 2 < 63){                   // issue x(t+2) into held regs
        int tk = sm.tok[t+2][xr];
        const float* e = ((t+2) < 31 ? enc_emb : dec_emb) + (size_t)tk*256 + xk;
        xh0 = *(const float4*)e; xh1 = *(const float4*)(e + 4);
      }
    }
    __syncthreads();                                           // SD
  };

  for (int t = 0; t <= 30; ++t) step(t);
  if (myl == 0) LOADW(1);   // dec W1 (first used by l1(31)); l2(30) still enc W2
  step(31);
  if (myl == 1) LOADW(1);   // dec W2 (first used computing l2(31) at step 32)
  for (int t = 32; t <= 63; ++t) step(t);

  // ---- tail fc: h2(62) (in H2t after step 63's readback) -> out row 31
  if (wv == 1){
    const int b = (w << 1) + (lane >> 5), v = (lane >> 3) & 3, q8 = lane & 7;
    const u16* hrow = &sm.H2t[b][q8 << 5];
    const float* wr = &sm.fcw[v][q8 << 5];
    float s = 0.f;
    #pragma unroll
    for (int f = 0; f < 4; f++){
      bf16x8 hv = *(const bf16x8*)(hrow + (f << 3));
      const float4 wa = *(const float4*)(wr + (f << 3));
      const float4 wb = *(const float4*)(wr + (f << 3) + 4);
      s += bf2f((u16)hv[0])*wa.x + bf2f((u16)hv[1])*wa.y
         + bf2f((u16)hv[2])*wa.z + bf2f((u16)hv[3])*wa.w
         + bf2f((u16)hv[4])*wb.x + bf2f((u16)hv[5])*wb.y
         + bf2f((u16)hv[6])*wb.z + bf2f((u16)hv[7])*wb.w;
    }
    s += __shfl_xor(s, 1); s += __shfl_xor(s, 2); s += __shfl_xor(s, 4);
    s += sm.fcb[v];
    float m = fmaxf(s, __shfl_xor(s, 8)); m = fmaxf(m, __shfl_xor(m, 16));
    float e_ = __expf(s - m);
    float es = e_ + __shfl_xor(e_, 8); es += __shfl_xor(es, 16);
    if (q8 == 0)
      out[((size_t)31*512 + wgb0 + b)*4 + v] = s - m - __logf(es);
  }
}

extern "C" void kernel_launch(void* const* d_in, const int* in_sizes, int n_in,
                              void* d_out, int out_size, void* d_ws, size_t ws_size,
                              hipStream_t stream){
  const int*   src     = (const int*)  d_in[0];
  const float* enc_emb = (const float*)d_in[2];
  const float* enc_Wih = (const float*)d_in[3];
  const float* enc_Whh = (const float*)d_in[4];
  const float* enc_bih = (const float*)d_in[5];
  const float* enc_bhh = (const float*)d_in[6];
  const float* dec_emb = (const float*)d_in[7];
  const float* dec_Wih = (const float*)d_in[8];
  const float* dec_Whh = (const float*)d_in[9];
  const float* dec_bih = (const float*)d_in[10];
  const float* dec_bhh = (const float*)d_in[11];
  const float* fcW     = (const float*)d_in[12];
  const float* fcb     = (const float*)d_in[13];
  float* out = (float*)d_out;
  (void)in_sizes; (void)n_in; (void)out_size; (void)ws_size;

  // ws: wpack 4MB | bpack 16KB | H1 512KB (2-parity) | H2 512KB | flags 8KB
  u16*   wpack = (u16*)d_ws;
  float* bpack = (float*)((char*)d_ws + 4194304);
  u32*   H1    = (u32*)((char*)d_ws + 4194304 + 16384);
  u32*   H2    = (u32*)((char*)d_ws + 4194304 + 16384 + 524288);
  u32*   flags = (u32*)((char*)d_ws + 4194304 + 16384 + 1048576);

  pack_all<<<8209, 256, 0, stream>>>(enc_Wih, enc_Whh, dec_Wih, dec_Whh,
                                     enc_bih, enc_bhh, dec_bih, dec_bhh,
                                     wpack, bpack, flags);
  lstm_main<<<256, 512, 0, stream>>>(src, enc_emb, dec_emb, wpack, bpack,
                                     fcW, fcb, out, H1, H2, flags);
}